// Round 6
// baseline (319.930 us; speedup 1.0000x reference)
//
#include <hip/hip_runtime.h>

#define NN     4096
#define MAXD   32      // degree cap (WS k=4 max degree ~12)
#define WUNR   8       // fully-unrolled ELL width; rows with c>8 take tail loop
#define TB     4       // tokens per round
#define ROUNDS 16      // rounds per block -> 64 tokens/block
#define BLK    1024
#define QN     (NN / BLK)

// Phase 1: build padded ELL (column-major [j][o]) of W*M, deterministically.
// One wave per output row o; ballot + prefix popcount -> indices sorted
// ascending -> fixed fp32 summation order. float2 {idx bitcast, w}; padding {0,0}.
__global__ __launch_bounds__(64) void build_ell_kernel(
    const float* __restrict__ weight, const float* __restrict__ mask,
    float2* __restrict__ ell, int* __restrict__ cnt) {
  const int o = blockIdx.x;
  const int lane = threadIdx.x;
  if (lane < MAXD) {
    float2 z; z.x = __uint_as_float(0u); z.y = 0.0f;
    ell[(size_t)lane * NN + o] = z;
  }
  __syncthreads();
  const float* mrow = mask + (size_t)o * NN;
  const float* wrow = weight + (size_t)o * NN;
  int count = 0;
  for (int base = 0; base < NN; base += 64) {
    const float m = mrow[base + lane];
    const bool nz = (m != 0.0f);
    const unsigned long long bal = __ballot(nz);
    if (nz) {
      const int pos = count + __popcll(bal & ((1ull << lane) - 1ull));
      if (pos < MAXD) {
        float2 e;
        e.x = __uint_as_float((unsigned)(base + lane));
        e.y = wrow[base + lane] * m;   // m == 1.0 exactly
        ell[(size_t)pos * NN + o] = e;
      }
    }
    count += __popcll(bal);
  }
  if (lane == 0) cnt[o] = (count < MAXD) ? count : MAXD;
}

// Phase 2: persistent double-buffered SpMM.
//  - ELL entries / cnt / bias hoisted to registers once (reused 16 rounds);
//    __launch_bounds__(1024) -> 128-VGPR cap, fits ~110 live regs, still 16 waves/CU.
//  - Per round: issue next round's 16 coalesced x loads (latency hides under
//    compute), gather-compute from xs[cur] (ds_read_b128 = 4 tokens/index),
//    coalesced out stores (left in flight), ds_write prefetch -> xs[cur^1].
//  - Raw s_barrier + lgkmcnt(0) only: NO vmcnt(0) drain per round, so stores
//    and prefetch loads stay outstanding across the barrier.
__global__ __launch_bounds__(BLK) void ws_spmm_kernel(
    const float* __restrict__ x, const float* __restrict__ bias,
    const float2* __restrict__ ell, const int* __restrict__ cnt,
    float* __restrict__ out) {
  __shared__ float4 xs[2][NN];                       // 2 x 64 KiB
  const int tid = threadIdx.x;
  const size_t tok0 = (size_t)blockIdx.x * (TB * ROUNDS);

  // Hoist this thread's QN output rows of ELL + cnt + bias (static-indexed).
  float2 e[QN][WUNR];
  int   cn[QN];
  float bs[QN];
#pragma unroll
  for (int q = 0; q < QN; ++q) {
    const int o = q * BLK + tid;
    cn[q] = cnt[o];
    bs[q] = bias[o];
#pragma unroll
    for (int j = 0; j < WUNR; ++j)
      e[q][j] = ell[(size_t)j * NN + o];
  }

  // Stage round 0.
  {
    const float* __restrict__ xb = x + tok0 * NN;
#pragma unroll
    for (int i = 0; i < QN; ++i) {
      const int c2 = tid + i * BLK;
      float4 v;
      v.x = xb[0 * NN + c2];
      v.y = xb[1 * NN + c2];
      v.z = xb[2 * NN + c2];
      v.w = xb[3 * NN + c2];
      xs[0][c2] = v;
    }
  }
  asm volatile("s_waitcnt lgkmcnt(0)" ::: "memory");
  __builtin_amdgcn_s_barrier();

  for (int it = 0; it < ROUNDS; ++it) {
    const int cur = it & 1;

    // Prefetch next round's 4 token rows into registers.
    float xr[TB][QN];
    if (it + 1 < ROUNDS) {
      const float* __restrict__ xb = x + (tok0 + (size_t)(it + 1) * TB) * NN;
#pragma unroll
      for (int i = 0; i < QN; ++i) {
        const int c2 = tid + i * BLK;
#pragma unroll
        for (int t = 0; t < TB; ++t)
          xr[t][i] = xb[t * NN + c2];
      }
    }

    // Compute current round (q fully unrolled; e/cn/bs in registers).
    const size_t t0 = tok0 + (size_t)it * TB;
#pragma unroll
    for (int q = 0; q < QN; ++q) {
      const int o = q * BLK + tid;
      float a0 = 0.f, a1 = 0.f, a2 = 0.f, a3 = 0.f;
#pragma unroll
      for (int j = 0; j < WUNR; ++j) {
        const unsigned ix = __float_as_uint(e[q][j].x);
        const float w = e[q][j].y;
        const float4 xv = xs[cur][ix];               // ds_read_b128: 4 tokens
        a0 = fmaf(xv.x, w, a0);
        a1 = fmaf(xv.y, w, a1);
        a2 = fmaf(xv.z, w, a2);
        a3 = fmaf(xv.w, w, a3);
      }
      for (int j = WUNR; j < cn[q]; ++j) {           // rare tail (degree > 8)
        const float2 et = ell[(size_t)j * NN + o];
        const unsigned ix = __float_as_uint(et.x);
        const float w = et.y;
        const float4 xv = xs[cur][ix];
        a0 = fmaf(xv.x, w, a0);
        a1 = fmaf(xv.y, w, a1);
        a2 = fmaf(xv.z, w, a2);
        a3 = fmaf(xv.w, w, a3);
      }
      float* op = out + t0 * NN + o;
      op[0]      = a0 + bs[q];
      op[NN]     = a1 + bs[q];
      op[2 * NN] = a2 + bs[q];
      op[3 * NN] = a3 + bs[q];
    }

    // Write prefetched regs into the other buffer (compiler emits counted
    // vmcnt wait for the xr loads only; stores stay in flight).
    if (it + 1 < ROUNDS) {
      const int nxt = cur ^ 1;
#pragma unroll
      for (int i = 0; i < QN; ++i) {
        const int c2 = tid + i * BLK;
        xs[nxt][c2] = make_float4(xr[0][i], xr[1][i], xr[2][i], xr[3][i]);
      }
    }
    asm volatile("s_waitcnt lgkmcnt(0)" ::: "memory");
    __builtin_amdgcn_s_barrier();
  }
}

extern "C" void kernel_launch(void* const* d_in, const int* in_sizes, int n_in,
                              void* d_out, int out_size, void* d_ws, size_t ws_size,
                              hipStream_t stream) {
  const float* x      = (const float*)d_in[0];
  const float* weight = (const float*)d_in[1];
  const float* bias   = (const float*)d_in[2];
  const float* mask   = (const float*)d_in[3];
  float* out = (float*)d_out;

  char* ws = (char*)d_ws;
  float2* ell = (float2*)ws;                                     // 1 MiB
  int*    cnt = (int*)(ws + (size_t)MAXD * NN * sizeof(float2)); // 16 KiB

  const int tokens = in_sizes[0] / NN;               // 16384

  build_ell_kernel<<<NN, 64, 0, stream>>>(weight, mask, ell, cnt);
  ws_spmm_kernel<<<tokens / (TB * ROUNDS), BLK, 0, stream>>>(x, bias, ell, cnt, out);
}